// Round 1
// baseline (9480.746 us; speedup 1.0000x reference)
//
#include <hip/hip_runtime.h>
#include <stdint.h>

#define H      1000
#define HPAD   1024
#define VOCAB  32000
#define TSTEPS 4096
#define MOUT   4097   // T+1 rows of output
#define MPAD   4224   // 33*128

// ---------- helpers ----------
__device__ __forceinline__ unsigned short f2bf(float f) {
    unsigned u = __float_as_uint(f);
    unsigned r = (u + 0x7fffu + ((u >> 16) & 1u)) >> 16;
    return (unsigned short)r;
}

typedef __bf16  bf16x8 __attribute__((ext_vector_type(8)));
typedef float   f32x4  __attribute__((ext_vector_type(4)));

// ---------- kernel 1: W_hy fp32 [32000][1000] -> bf16 [32000][1024] (pad 0) ----------
__global__ __launch_bounds__(1024) void convert_why(const float* __restrict__ W,
                                                    unsigned short* __restrict__ O) {
    int r = blockIdx.x;
    int c = threadIdx.x;
    unsigned short v = 0;
    if (c < H) v = f2bf(W[(size_t)r * H + c]);
    O[(size_t)r * HPAD + c] = v;
}

// ---------- kernel 2: persistent RNN scan ----------
// grid = 256 blocks x 64 threads. block b owns rows 4b..4b+3.
// h broadcast via h_comm[2][1024] u64 {epoch<<32 | f32 bits}, agent-scope atomics.
__global__ __launch_bounds__(64) void scan_kernel(const int*   __restrict__ tok,
                                                  const float* __restrict__ h0,
                                                  const float* __restrict__ Wxh,
                                                  const float* __restrict__ Whh,
                                                  const float* __restrict__ Bh,
                                                  unsigned long long* __restrict__ h_comm,
                                                  unsigned short* __restrict__ all_h) {
    __shared__ int tokLDS[TSTEPS];
    const int b    = blockIdx.x;    // 0..255
    const int lane = threadIdx.x;   // 0..63

    // preload all tokens into LDS (coalesced, one-time)
    for (int j = 0; j < TSTEPS / 64; ++j)
        tokLDS[lane + 64 * j] = tok[lane + 64 * j];
    __syncthreads();

    // W_hh rows 4b..4b+3, cols lane+64j, in registers (coalesced load, one-time)
    const int row0 = 4 * b;
    float Wreg[4][16];
#pragma unroll
    for (int i = 0; i < 4; ++i) {
        const int r = row0 + i;
#pragma unroll
        for (int j = 0; j < 16; ++j) {
            const int c = lane + 64 * j;
            Wreg[i][j] = (r < H && c < H) ? Whh[(size_t)r * H + c] : 0.0f;
        }
    }

    const bool pub      = (lane < 4);
    const int  myrow    = row0 + lane;            // valid for pub lanes
    const bool rowvalid = pub && (myrow < H);
    float bias = rowvalid ? Bh[myrow] : 0.0f;

    // h_0
    float hv[16];
#pragma unroll
    for (int j = 0; j < 16; ++j) {
        const int c = lane + 64 * j;
        hv[j] = (c < H) ? h0[c] : 0.0f;
    }
    // all_h row 0 (block 0 writes all 1024 cols)
    if (b == 0) {
#pragma unroll
        for (int j = 0; j < 16; ++j)
            all_h[lane + 64 * j] = f2bf(hv[j]);
    }
    // prefetch x for step 1 (token[0])
    float xv = 0.0f;
    if (rowvalid) xv = Wxh[(size_t)myrow * VOCAB + tokLDS[0]];

    for (int t = 1; t <= TSTEPS; ++t) {
        // ---- compute h_t rows from hv (= h_{t-1}) ----
        float a0 = 0.f, a1 = 0.f, a2 = 0.f, a3 = 0.f;
#pragma unroll
        for (int j = 0; j < 16; ++j) {
            const float h = hv[j];
            a0 = fmaf(Wreg[0][j], h, a0);
            a1 = fmaf(Wreg[1][j], h, a1);
            a2 = fmaf(Wreg[2][j], h, a2);
            a3 = fmaf(Wreg[3][j], h, a3);
        }
        // butterfly reduce across the 64 lanes (all lanes end with full sums)
#pragma unroll
        for (int m = 1; m < 64; m <<= 1) {
            a0 += __shfl_xor(a0, m);
            a1 += __shfl_xor(a1, m);
            a2 += __shfl_xor(a2, m);
            a3 += __shfl_xor(a3, m);
        }
        const int buf = t & 1;
        if (pub) {
            float s = (lane == 0) ? a0 : (lane == 1) ? a1 : (lane == 2) ? a2 : a3;
            float val = 0.0f;
            if (rowvalid) val = tanhf(s + xv + bias);
            unsigned long long packed =
                ((unsigned long long)(unsigned)t << 32) | (unsigned long long)__float_as_uint(val);
            __hip_atomic_store(&h_comm[(size_t)buf * HPAD + myrow], packed,
                               __ATOMIC_RELAXED, __HIP_MEMORY_SCOPE_AGENT);
            all_h[(size_t)t * HPAD + myrow] = f2bf(val);
            // prefetch x for step t+1 (uses token[t]) — hidden behind next poll+compute
            if (t < TSTEPS && myrow < H) xv = Wxh[(size_t)myrow * VOCAB + tokLDS[t]];
        }
        if (t == TSTEPS) break;

        // ---- poll h_t (refill hv for next step) ----
        unsigned long long v[16];
        bool ok;
        do {
            ok = true;
#pragma unroll
            for (int j = 0; j < 16; ++j) {
                v[j] = __hip_atomic_load(&h_comm[(size_t)buf * HPAD + lane + 64 * j],
                                         __ATOMIC_RELAXED, __HIP_MEMORY_SCOPE_AGENT);
            }
#pragma unroll
            for (int j = 0; j < 16; ++j) ok &= ((unsigned)(v[j] >> 32) == (unsigned)t);
        } while (!ok);
#pragma unroll
        for (int j = 0; j < 16; ++j) hv[j] = __uint_as_float((unsigned)v[j]);
    }
}

// ---------- kernel 3: C[4097][32000] = A[4097][1024] @ Bt[32000][1024]^T, bf16 MFMA ----------
// m97 recipe: 128x128 block tile, 4 waves in 2x2, each wave 4x4 of 16x16x32 MFMA,
// global_load_lds width 16, single-buffer 2-barrier K-loop, BK=32, K=1024.
__global__ __launch_bounds__(256) void gemm_bt(const unsigned short* __restrict__ A,
                                               const unsigned short* __restrict__ Bt,
                                               float* __restrict__ C) {
    __shared__ unsigned short sA[128 * 32];
    __shared__ unsigned short sB[128 * 32];

    const int tid   = threadIdx.x;
    const int nTile = blockIdx.x;   // 0..249
    const int mTile = blockIdx.y;   // 0..32
    const int wid   = tid >> 6;
    const int lane  = tid & 63;
    const int wm    = wid >> 1;     // 0..1
    const int wn    = wid & 1;      // 0..1
    const int lm    = lane & 15;
    const int lq    = lane >> 4;    // quad 0..3

    f32x4 acc[4][4] = {};

    const size_t aBase = (size_t)mTile * 128 * HPAD;
    const size_t bBase = (size_t)nTile * 128 * HPAD;
    const int r0  = tid >> 2;       // 0..63
    const int kc0 = tid & 3;        // 0..3 (8-elem chunk within BK=32)

    for (int kt = 0; kt < HPAD / 32; ++kt) {
        const int k0 = kt * 32;
        __syncthreads();
        // stage A tile: 128 rows x 32 k, 16B per lane, 2 chunks per thread
        __builtin_amdgcn_global_load_lds(
            (const __attribute__((address_space(1))) void*)(A + aBase + (size_t)r0 * HPAD + k0 + kc0 * 8),
            (__attribute__((address_space(3))) void*)(sA + tid * 8), 16, 0, 0);
        __builtin_amdgcn_global_load_lds(
            (const __attribute__((address_space(1))) void*)(A + aBase + (size_t)(r0 + 64) * HPAD + k0 + kc0 * 8),
            (__attribute__((address_space(3))) void*)(sA + (tid + 256) * 8), 16, 0, 0);
        __builtin_amdgcn_global_load_lds(
            (const __attribute__((address_space(1))) void*)(Bt + bBase + (size_t)r0 * HPAD + k0 + kc0 * 8),
            (__attribute__((address_space(3))) void*)(sB + tid * 8), 16, 0, 0);
        __builtin_amdgcn_global_load_lds(
            (const __attribute__((address_space(1))) void*)(Bt + bBase + (size_t)(r0 + 64) * HPAD + k0 + kc0 * 8),
            (__attribute__((address_space(3))) void*)(sB + (tid + 256) * 8), 16, 0, 0);
        __syncthreads();

        bf16x8 af[4], bfr[4];
#pragma unroll
        for (int i = 0; i < 4; ++i)
            af[i] = *(const bf16x8*)(sA + (wm * 64 + i * 16 + lm) * 32 + lq * 8);
#pragma unroll
        for (int j = 0; j < 4; ++j)
            bfr[j] = *(const bf16x8*)(sB + (wn * 64 + j * 16 + lm) * 32 + lq * 8);
#pragma unroll
        for (int i = 0; i < 4; ++i)
#pragma unroll
            for (int j = 0; j < 4; ++j)
                acc[i][j] = __builtin_amdgcn_mfma_f32_16x16x32_bf16(af[i], bfr[j], acc[i][j], 0, 0, 0);
    }

    const int rowBase = mTile * 128 + wm * 64;
    const int colBase = nTile * 128 + wn * 64;
#pragma unroll
    for (int i = 0; i < 4; ++i)
#pragma unroll
        for (int j = 0; j < 4; ++j) {
            const int col = colBase + j * 16 + lm;
#pragma unroll
            for (int r = 0; r < 4; ++r) {
                const int row = rowBase + i * 16 + lq * 4 + r;
                if (row < MOUT) C[(size_t)row * VOCAB + col] = acc[i][j][r];
            }
        }
}

// ---------- launch ----------
extern "C" void kernel_launch(void* const* d_in, const int* in_sizes, int n_in,
                              void* d_out, int out_size, void* d_ws, size_t ws_size,
                              hipStream_t stream) {
    const int*   tok = (const int*)  d_in[0];
    const float* h0  = (const float*)d_in[1];
    const float* Wxh = (const float*)d_in[2];
    const float* Whh = (const float*)d_in[3];
    const float* Why = (const float*)d_in[4];
    const float* Bh  = (const float*)d_in[5];
    float* out = (float*)d_out;

    char* ws = (char*)d_ws;
    // layout: h_comm (16 KB) | all_h bf16 [4224][1024] (8.65 MB) | W_hy bf16 [32000][1024] (65.5 MB)
    unsigned long long* h_comm = (unsigned long long*)(ws);
    unsigned short*     all_h  = (unsigned short*)(ws + 16384);
    unsigned short*     why_bf = (unsigned short*)(ws + 16384 + (size_t)MPAD * HPAD * 2);

    convert_why<<<dim3(VOCAB), dim3(1024), 0, stream>>>(Why, why_bf);
    scan_kernel<<<dim3(256), dim3(64), 0, stream>>>(tok, h0, Wxh, Whh, Bh, h_comm, all_h);
    gemm_bt<<<dim3(VOCAB / 128, MPAD / 128), dim3(256), 0, stream>>>(all_h, why_bf, out);
}